// Round 15
// baseline (1149.745 us; speedup 1.0000x reference)
//
#include <hip/hip_runtime.h>
#include <hip/hip_bf16.h>
#include <stdint.h>

typedef short  bf16x8_t __attribute__((ext_vector_type(8)));
typedef short  bf16x4_t __attribute__((ext_vector_type(4)));
typedef float  f32x4_t  __attribute__((ext_vector_type(4)));
typedef unsigned short u16;
typedef unsigned int   u32;

#define DEV __device__ __forceinline__

DEV u16 f2bf(float f){
  u32 u = __float_as_uint(f);
  u += 0x7fffu + ((u >> 16) & 1u);     // RNE
  return (u16)(u >> 16);
}
DEV float bf2f(u16 h){ return __uint_as_float(((u32)h) << 16); }

DEV void gl16(const void* g, void* l){
  __builtin_amdgcn_global_load_lds(
      (const __attribute__((address_space(1))) void*)g,
      (__attribute__((address_space(3))) void*)l, 16, 0, 0);
}

#define BAR() __builtin_amdgcn_s_barrier()
#define WL8() asm volatile("s_waitcnt lgkmcnt(8)" ::: "memory")
#define WL0() asm volatile("s_waitcnt lgkmcnt(0)" ::: "memory")

// ---------------- f32 -> bf16 convert (8 elems/thread) ----------------
__global__ __launch_bounds__(256) void cvt_k(const float* __restrict__ in,
                                             u16* __restrict__ out, int n8){
  int i = blockIdx.x * 256 + threadIdx.x;
  if (i >= n8) return;
  const float4* p = (const float4*)in;
  float4 a = p[(size_t)i*2], b = p[(size_t)i*2+1];
  bf16x8_t o;
  o[0]=(short)f2bf(a.x); o[1]=(short)f2bf(a.y); o[2]=(short)f2bf(a.z); o[3]=(short)f2bf(a.w);
  o[4]=(short)f2bf(b.x); o[5]=(short)f2bf(b.y); o[6]=(short)f2bf(b.z); o[7]=(short)f2bf(b.w);
  *(bf16x8_t*)(out + (size_t)i*8) = o;
}

// ---- cvt3: three D*D f32 -> one concatenated bf16 buffer (n8each = 2^19) ----
__global__ __launch_bounds__(256) void cvt3_k(const float* __restrict__ s0,
                                              const float* __restrict__ s1,
                                              const float* __restrict__ s2,
                                              u16* __restrict__ out){
  int i = blockIdx.x * 256 + threadIdx.x;
  int mat = i >> 19;                 // n8each = 524288
  int j = i & 524287;
  const float* src = (mat==0) ? s0 : (mat==1) ? s1 : s2;
  const float4* p = (const float4*)src;
  float4 a = p[(size_t)j*2], b = p[(size_t)j*2+1];
  bf16x8_t o;
  o[0]=(short)f2bf(a.x); o[1]=(short)f2bf(a.y); o[2]=(short)f2bf(a.z); o[3]=(short)f2bf(a.w);
  o[4]=(short)f2bf(b.x); o[5]=(short)f2bf(b.y); o[6]=(short)f2bf(b.z); o[7]=(short)f2bf(b.w);
  *(bf16x8_t*)(out + (size_t)i*8) = o;
}

// ---------------- RMSNorm: fp32 row (D=2048) -> bf16 ----------------
__global__ __launch_bounds__(256) void rmsnorm_k(const float* __restrict__ x,
                                                 const float* __restrict__ w,
                                                 u16* __restrict__ y){
  int row = blockIdx.x, t = threadIdx.x;
  const float4* xr = (const float4*)(x + (size_t)row*2048);
  float4 a = xr[t*2], b = xr[t*2+1];
  float ss = a.x*a.x+a.y*a.y+a.z*a.z+a.w*a.w + b.x*b.x+b.y*b.y+b.z*b.z+b.w*b.w;
  #pragma unroll
  for (int m = 32; m; m >>= 1) ss += __shfl_xor(ss, m, 64);
  __shared__ float red[4];
  if ((t & 63) == 0) red[t >> 6] = ss;
  __syncthreads();
  float tot = red[0]+red[1]+red[2]+red[3];
  float rs = rsqrtf(tot * (1.0f/2048.0f) + 1e-6f);
  const float4* wr = (const float4*)w;
  float4 wa = wr[t*2], wb = wr[t*2+1];
  bf16x8_t o;
  o[0]=(short)f2bf(a.x*rs*wa.x); o[1]=(short)f2bf(a.y*rs*wa.y);
  o[2]=(short)f2bf(a.z*rs*wa.z); o[3]=(short)f2bf(a.w*rs*wa.w);
  o[4]=(short)f2bf(b.x*rs*wb.x); o[5]=(short)f2bf(b.y*rs*wb.y);
  o[6]=(short)f2bf(b.z*rs*wb.z); o[7]=(short)f2bf(b.w*rs*wb.w);
  *(bf16x8_t*)(y + (size_t)row*2048 + t*8) = o;
}

// ---- RMSNorm2: h = x(f32) + t1(bf16); y = rmsnorm(h)*w -> bf16 ----
__global__ __launch_bounds__(256) void rmsnorm2_k(const float* __restrict__ x,
                                                  const u16* __restrict__ t1,
                                                  const float* __restrict__ w,
                                                  u16* __restrict__ y){
  int row = blockIdx.x, t = threadIdx.x;
  const float4* xr = (const float4*)(x + (size_t)row*2048);
  float4 a = xr[t*2], b = xr[t*2+1];
  bf16x8_t tv = *(const bf16x8_t*)(t1 + (size_t)row*2048 + t*8);
  float h[8];
  h[0]=a.x+bf2f((u16)tv[0]); h[1]=a.y+bf2f((u16)tv[1]);
  h[2]=a.z+bf2f((u16)tv[2]); h[3]=a.w+bf2f((u16)tv[3]);
  h[4]=b.x+bf2f((u16)tv[4]); h[5]=b.y+bf2f((u16)tv[5]);
  h[6]=b.z+bf2f((u16)tv[6]); h[7]=b.w+bf2f((u16)tv[7]);
  float ss = 0.f;
  #pragma unroll
  for (int j=0;j<8;j++) ss += h[j]*h[j];
  #pragma unroll
  for (int m = 32; m; m >>= 1) ss += __shfl_xor(ss, m, 64);
  __shared__ float red[4];
  if ((t & 63) == 0) red[t >> 6] = ss;
  __syncthreads();
  float tot = red[0]+red[1]+red[2]+red[3];
  float rs = rsqrtf(tot * (1.0f/2048.0f) + 1e-6f);
  const float4* wr = (const float4*)w;
  float4 wa = wr[t*2], wb = wr[t*2+1];
  bf16x8_t o;
  o[0]=(short)f2bf(h[0]*rs*wa.x); o[1]=(short)f2bf(h[1]*rs*wa.y);
  o[2]=(short)f2bf(h[2]*rs*wa.z); o[3]=(short)f2bf(h[3]*rs*wa.w);
  o[4]=(short)f2bf(h[4]*rs*wb.x); o[5]=(short)f2bf(h[5]*rs*wb.y);
  o[6]=(short)f2bf(h[6]*rs*wb.z); o[7]=(short)f2bf(h[7]*rs*wb.w);
  *(bf16x8_t*)(y + (size_t)row*2048 + t*8) = o;
}

// ---------------- 2048x8192 transpose (V -> V^T), 64x64 tiles ----------------
__global__ __launch_bounds__(256) void transpose_k(const u16* __restrict__ in,
                                                   u16* __restrict__ out){
  __shared__ u16 tile[64*68];
  int tid = threadIdx.x;
  int tm = blockIdx.x >> 5, tn = blockIdx.x & 31;   // in: [8192][2048]
  const u16* src = in + (size_t)(tm*64)*2048 + tn*64;
  #pragma unroll
  for (int i=0;i<2;i++){
    int idx = i*256 + tid;
    int r = idx >> 3, c8 = (idx & 7)*8;
    *(bf16x8_t*)&tile[r*68 + c8] = *(const bf16x8_t*)(src + (size_t)r*2048 + c8);
  }
  __syncthreads();
  u16* dst = out + (size_t)(tn*64)*8192 + tm*64;
  #pragma unroll
  for (int i=0;i<2;i++){
    int idx = i*256 + tid;
    int oc = idx >> 3, r8 = (idx & 7)*8;
    bf16x8_t v;
    #pragma unroll
    for (int j=0;j<8;j++) v[j] = tile[(r8+j)*68 + oc];
    *(bf16x8_t*)(dst + (size_t)oc*8192 + r8) = v;
  }
}

// ---------------- GEMM: 256x256 tile, BK=64, 8-phase (r11, best) ----------
// EPI: 0 bf16; 1 silu->bf16; 2 v*aux(bf16) in-place; 4 f32 = v+aux+aux2;
//      6 QKV routed bf16 + fused RoPE on q,k (C=q, aux=k, aux2=v)

#define RA(BUF,MH) { \
  Ar[0][0]=*(const bf16x8_t*)(pA +BUF*16384+MH*4096);      \
  Ar[0][1]=*(const bf16x8_t*)(pAx+BUF*16384+MH*4096);      \
  Ar[1][0]=*(const bf16x8_t*)(pA +BUF*16384+MH*4096+1024); \
  Ar[1][1]=*(const bf16x8_t*)(pAx+BUF*16384+MH*4096+1024); \
  Ar[2][0]=*(const bf16x8_t*)(pA +BUF*16384+MH*4096+2048); \
  Ar[2][1]=*(const bf16x8_t*)(pAx+BUF*16384+MH*4096+2048); \
  Ar[3][0]=*(const bf16x8_t*)(pA +BUF*16384+MH*4096+3072); \
  Ar[3][1]=*(const bf16x8_t*)(pAx+BUF*16384+MH*4096+3072); }
#define RB(DST,BUF,NHL) { \
  DST[0][0]=*(const bf16x8_t*)(pB +BUF*16384+NHL*2048);      \
  DST[0][1]=*(const bf16x8_t*)(pBx+BUF*16384+NHL*2048);      \
  DST[1][0]=*(const bf16x8_t*)(pB +BUF*16384+NHL*2048+1024); \
  DST[1][1]=*(const bf16x8_t*)(pBx+BUF*16384+NHL*2048+1024); }
#define STG_A(BUF,HALF,COL) { \
  gl16(gA + (COL) + HALF*K128,       dA + BUF*16384 + HALF*8192); \
  gl16(gA + (COL) + HALF*K128 + K64, dA + BUF*16384 + HALF*8192 + 4096); }
#define STG_B(BUF,HALF,COL) { \
  gl16(gB + (COL) + HALF*K128,       dB + BUF*16384 + HALF*8192); \
  gl16(gB + (COL) + HALF*K128 + K64, dB + BUF*16384 + HALF*8192 + 4096); }

// 16 MFMA cluster, kk outermost (r11)
DEV void MMQ(bf16x8_t (&a)[4][2], bf16x8_t (&b)[2][2], int mh, int nhl,
             f32x4_t (&acc)[8][4]){
  __builtin_amdgcn_s_setprio(1);
  #pragma unroll
  for (int kk=0;kk<2;kk++)
    #pragma unroll
    for (int mi=0;mi<4;mi++)
      #pragma unroll
      for (int nj=0;nj<2;nj++)
        acc[mh*4+mi][nhl*2+nj] = __builtin_amdgcn_mfma_f32_16x16x32_bf16(
            a[mi][kk], b[nj][kk], acc[mh*4+mi][nhl*2+nj], 0,0,0);
  __builtin_amdgcn_s_setprio(0);
}

template<int EPI>
__global__ __launch_bounds__(512, 2) void gemm_bt(const u16* __restrict__ A,
                                                  const u16* __restrict__ B,
                                                  void* __restrict__ C,
                                                  const void* __restrict__ aux,
                                                  const void* __restrict__ aux2,
                                                  const float* __restrict__ fc,
                                                  const float* __restrict__ fs,
                                                  int M, int N, int K){
  __shared__ __align__(16) u16 sA[2][2][8192];   // [buf][rowhalf][128x64] 64KB
  __shared__ __align__(16) u16 sB[2][2][8192];   // 64KB
  int tid = threadIdx.x, lane = tid & 63, wave = tid >> 6;
  int l15 = lane & 15, l4 = lane >> 4;
  int nbn = N / 256;
  int nwg = gridDim.x, bid = blockIdx.x;
  int qq = nwg >> 3, rr = nwg & 7;
  int xc = bid & 7, yy = bid >> 3;
  int wg = (xc < rr ? xc*(qq+1) : rr*(qq+1) + (xc-rr)*qq) + yy;
  int tm = wg / nbn, tn = wg % nbn;
  size_t m0 = (size_t)tm*256, n0 = (size_t)tn*256;
  const u16* Ag = A + m0*K;
  const u16* Bg = B + n0*K;
  int wm = wave >> 2, wn = wave & 3;           // 2 x 4 wave grid
  int bh = wn >> 1, wn1 = wn & 1;

  // hoisted LDS read lane pointers (kk=0 / kk=1 chunk forms)
  int ch0 = l4 ^ (l15 & 7);
  const u16* pA  = &sA[0][wm][l15*64 + ch0*8];
  const u16* pAx = &sA[0][wm][l15*64 + (ch0^4)*8];
  const u16* pB  = &sB[0][bh][(wn1*64 + l15)*64 + ch0*8];
  const u16* pBx = &sB[0][bh][(wn1*64 + l15)*64 + (ch0^4)*8];
  // hoisted staging bases
  int r0 = tid >> 3;
  int lg = (tid & 7) ^ (r0 & 7);
  const u16* gA = Ag + (size_t)r0*K + lg*8;
  const u16* gB = Bg + (size_t)r0*K + lg*8;
  size_t K64 = (size_t)K*64, K128 = K64*2;
  u16* dA = &sA[0][0][tid*8];
  u16* dB = &sB[0][0][tid*8];

  f32x4_t acc[8][4];
  #pragma unroll
  for (int i=0;i<8;i++)
    #pragma unroll
    for (int j=0;j<4;j++)
      acc[i][j] = (f32x4_t){0.f,0.f,0.f,0.f};
  bf16x8_t Ar[4][2], Br0[2][2], Br1[2][2];
  int nk = K / 64;

  STG_A(0,0,0); STG_A(0,1,0);
  STG_B(0,0,0); STG_B(0,1,0);
  STG_B(1,0,(size_t)64); STG_B(1,1,(size_t)64);
  asm volatile("s_waitcnt vmcnt(4)" ::: "memory");
  BAR();

  for (int i=0; i<nk/2; ++i){
    int T0 = 2*i;
    bool s2 = (T0+2 < nk), s3 = (T0+3 < nk);
    size_t c1 = (size_t)(T0+1)*64, c2 = (size_t)(T0+2)*64, c3 = (size_t)(T0+3)*64;
    // p0
    RA(0,0); RB(Br0,0,0);
    STG_A(1,0,c1);
    WL8(); BAR(); WL0();
    MMQ(Ar, Br0, 0, 0, acc);
    BAR();
    // p1
    RB(Br1,0,1);
    STG_A(1,1,c1);
    BAR(); WL0();
    MMQ(Ar, Br1, 0, 1, acc);
    BAR();
    // p2
    RA(0,1);
    if (s2) STG_B(0,0,c2);
    BAR(); WL0();
    MMQ(Ar, Br0, 1, 0, acc);
    BAR();
    // p3
    if (s2){
      STG_B(0,1,c2);
      asm volatile("s_waitcnt vmcnt(4)" ::: "memory");
    } else {
      asm volatile("s_waitcnt vmcnt(0)" ::: "memory");
    }
    BAR(); WL0();
    MMQ(Ar, Br1, 1, 1, acc);
    BAR();
    // p4
    RA(1,0); RB(Br0,1,0);
    if (s2) STG_A(0,0,c2);
    WL8(); BAR(); WL0();
    MMQ(Ar, Br0, 0, 0, acc);
    BAR();
    // p5
    RB(Br1,1,1);
    if (s2) STG_A(0,1,c2);
    BAR(); WL0();
    MMQ(Ar, Br1, 0, 1, acc);
    BAR();
    // p6
    RA(1,1);
    if (s3) STG_B(1,0,c3);
    BAR(); WL0();
    MMQ(Ar, Br0, 1, 0, acc);
    BAR();
    // p7
    if (s3){
      STG_B(1,1,c3);
      asm volatile("s_waitcnt vmcnt(4)" ::: "memory");
    } else {
      asm volatile("s_waitcnt vmcnt(0)" ::: "memory");
    }
    BAR(); WL0();
    MMQ(Ar, Br1, 1, 1, acc);
    BAR();
  }

  #pragma unroll
  for (int am=0; am<8; am++)
    #pragma unroll
    for (int ni=0; ni<4; ni++)
      #pragma unroll
      for (int r=0; r<4; r++){
        float v = acc[am][ni][r];
        size_t rowg = m0 + (am&3)*16 + (am>>2)*64 + wm*128 + l4*4 + r;
        size_t colg = n0 + wn*64 + ni*16 + l15;
        size_t idx = rowg * (size_t)N + colg;
        if constexpr (EPI == 0){
          ((u16*)C)[idx] = f2bf(v);
        } else if constexpr (EPI == 1){
          float s = v / (1.0f + __expf(-v));
          ((u16*)C)[idx] = f2bf(s);
        } else if constexpr (EPI == 2){
          float a = bf2f(((const u16*)aux)[idx]);
          ((u16*)C)[idx] = f2bf(v * a);
        } else if constexpr (EPI == 4){
          float a = ((const float*)aux)[idx];
          float b2 = bf2f(((const u16*)aux2)[idx]);
          ((float*)C)[idx] = v + a + b2;
        } else {  // EPI 6: QKV routed + fused RoPE on q,k
          int mat = (int)(colg >> 11);           // block-uniform (256 | 2048)
          int col = (int)(colg & 2047);
          u16* dst = (mat==0) ? (u16*)C : (mat==1) ? (u16*)aux : (u16*)aux2;
          float o = v;
          if (mat < 2){
            int s  = (int)(rowg & 2047);         // token position
            int ii = (col & 127) >> 1;           // pair index within head
            float c  = fc[s*64 + ii];
            float sn = fs[s*64 + ii];
            float vp = __shfl_xor(v, 1, 64);     // partner column (l15^1)
            o = (col & 1) ? (vp*sn + v*c) : (v*c - vp*sn);
          }
          dst[rowg*2048 + col] = f2bf(o);
        }
      }
}

// ---------------- causal flash attention (swapped QK^T, V^T input) ----------
// Fixed-reference softmax; double-buffered K/V staging with counted vmcnt.
__global__ __launch_bounds__(256) void attn_k(const u16* __restrict__ Q,
                                              const u16* __restrict__ K,
                                              const u16* __restrict__ VT,
                                              u16* __restrict__ O){
  __shared__ __align__(16) u16 sK[2][32*128];
  __shared__ __align__(16) u16 sVT[2][128*32];
  int tid = threadIdx.x, lane = tid & 63, wave = tid >> 6;
  int bid = blockIdx.x;
  int qt = 31 - (bid >> 6);
  int bh = bid & 63; int b = bh >> 4, h = bh & 15;
  int l15 = lane & 15, l4 = lane >> 4;
  size_t base = ((size_t)b*2048)*2048 + (size_t)h*128;
  const u16* VTg0 = VT + ((size_t)h*128)*8192 + (size_t)b*2048;
  int qr0 = qt*64 + wave*16;
  int qrow = qr0 + l15;
  bf16x8_t qf[4];
  #pragma unroll
  for (int s=0;s<4;s++)
    qf[s] = *(const bf16x8_t*)(Q + base + (size_t)qrow*2048 + s*32 + l4*8);

  f32x4_t oaccT[8];
  #pragma unroll
  for (int f=0;f<8;f++) oaccT[f] = (f32x4_t){0.f,0.f,0.f,0.f};
  float lrun = 0.f;

  const float cl2 = 0.08838834764831845f * 1.4426950408889634f;
  int nkt = (qt + 1) * 2;

  auto STG = [&](int t, int buf){
    const u16* Kg = K + base + (size_t)t*32*2048;
    #pragma unroll
    for (int i=0;i<2;i++){
      int c = i*256 + tid; int row = c>>4;
      gl16(Kg + (size_t)row*2048 + (size_t)(((c&15) ^ (row&7))*8), &sK[buf][c*8]);
    }
    #pragma unroll
    for (int i=0;i<2;i++){
      int c = i*256 + tid; int d = c>>2;
      gl16(VTg0 + (size_t)d*8192 + t*32 + (size_t)((((c&3) ^ ((d>>1)&3)))*8),
           &sVT[buf][c*8]);
    }
  };

  STG(0, 0);
  STG(1, 1);     // nkt >= 2 always

  for (int kt=0; kt<nkt; ++kt){
    if (kt < nkt-1) asm volatile("s_waitcnt vmcnt(4)" ::: "memory");
    else            asm volatile("s_waitcnt vmcnt(0)" ::: "memory");
    BAR();
    int buf = kt & 1;
    if (kt*32 <= qr0 + 15){
      f32x4_t sacc[2];
      sacc[0] = (f32x4_t){0.f,0.f,0.f,0.f};
      sacc[1] = (f32x4_t){0.f,0.f,0.f,0.f};
      __builtin_amdgcn_s_setprio(1);
      #pragma unroll
      for (int n=0;n<2;n++)
        #pragma unroll
        for (int s=0;s<4;s++){
          bf16x8_t kf = *(const bf16x8_t*)
              &sK[buf][(n*16 + l15)*128 + (((s*4 + l4) ^ (l15 & 7))*8)];
          sacc[n] = __builtin_amdgcn_mfma_f32_16x16x32_bf16(kf, qf[s], sacc[n], 0,0,0);
        }
      __builtin_amdgcn_s_setprio(0);
      float sum = 0.f;
      bf16x8_t pa;
      bool diag = (kt*32 + 31 > qr0);
      if (diag){
        #pragma unroll
        for (int j=0;j<8;j++){
          int n = j>>2, r = j&3;
          float p = exp2f(sacc[n][r] * cl2);
          int kg = kt*32 + n*16 + l4*4 + r;
          if (kg > qrow) p = 0.f;
          sum += p;
          pa[j] = (short)f2bf(p);
        }
      } else {
        #pragma unroll
        for (int j=0;j<8;j++){
          float p = exp2f(sacc[j>>2][j&3] * cl2);
          sum += p;
          pa[j] = (short)f2bf(p);
        }
      }
      sum += __shfl_xor(sum, 16, 64);
      sum += __shfl_xor(sum, 32, 64);
      lrun += sum;
      __builtin_amdgcn_s_setprio(1);
      #pragma unroll
      for (int f=0;f<8;f++){
        int d = f*16 + l15;
        bf16x4_t lo = *(const bf16x4_t*)&sVT[buf][d*32 + (((0*4 + l4) ^ (d & 6))*4)];
        bf16x4_t hi = *(const bf16x4_t*)&sVT[buf][d*32 + (((1*4 + l4) ^ (d & 6))*4)];
        bf16x8_t va;
        va[0]=lo[0]; va[1]=lo[1]; va[2]=lo[2]; va[3]=lo[3];
        va[4]=hi[0]; va[5]=hi[1]; va[6]=hi[2]; va[7]=hi[3];
        oaccT[f] = __builtin_amdgcn_mfma_f32_16x16x32_bf16(va, pa, oaccT[f], 0,0,0);
      }
      __builtin_amdgcn_s_setprio(0);
    }
    BAR();
    if (kt+2 < nkt) STG(kt+2, buf);
  }
  float inv = 1.0f / lrun;
  size_t orow = (size_t)b*2048 + qrow;
  #pragma unroll
  for (int f=0;f<8;f++){
    bf16x4_t ov;
    ov[0]=(short)f2bf(oaccT[f][0]*inv); ov[1]=(short)f2bf(oaccT[f][1]*inv);
    ov[2]=(short)f2bf(oaccT[f][2]*inv); ov[3]=(short)f2bf(oaccT[f][3]*inv);
    *(bf16x4_t*)(O + orow*2048 + h*128 + f*16 + l4*4) = ov;
  }
}

// ---------------- host ----------------
extern "C" void kernel_launch(void* const* d_in, const int* in_sizes, int n_in,
                              void* d_out, int out_size, void* d_ws, size_t ws_size,
                              hipStream_t stream){
  (void)in_sizes; (void)n_in; (void)out_size; (void)ws_size;
  const float* x   = (const float*)d_in[0];
  const float* fc  = (const float*)d_in[1];
  const float* fs  = (const float*)d_in[2];
  const float* wq  = (const float*)d_in[4];
  const float* wk  = (const float*)d_in[5];
  const float* wv  = (const float*)d_in[6];
  const float* wo  = (const float*)d_in[7];
  const float* w1  = (const float*)d_in[8];
  const float* w2  = (const float*)d_in[9];
  const float* w3  = (const float*)d_in[10];
  const float* anw = (const float*)d_in[11];
  const float* fnw = (const float*)d_in[12];
  float* out = (float*)d_out;
  char* ws = (char*)d_ws;

  const int M = 8192, D = 2048, HID = 5632;
  const size_t WB   = 25165824ull;   // 6144*2048*2 (QKV concat / reused buf)
  const size_t ACT2 = 33554432ull;   // 8192*2048*2

  u16* wbuf = (u16*)(ws);
  u16* xa   = (u16*)(ws + WB);                // rmsnorm(x); later attn O
  u16* qb   = (u16*)(ws + WB + ACT2);         // Q; later t1 = o@wo^T
  u16* kb   = (u16*)(ws + WB + 2*ACT2);       // K; later hf
  u16* vb   = (u16*)(ws + WB + 3*ACT2);       // V
  u16* g1   = (u16*)(ws + WB + 4*ACT2);       // VT (32MB) then g1 (88 MiB)
  u16* vt = g1;
  u16* t1 = qb;
  u16* hf = kb;

  rmsnorm_k<<<M, 256, 0, stream>>>(x, anw, xa);

  // fused QKV: concat weights [6144][2048]; one GEMM with routed epilogue
  // + fused RoPE on the q,k outputs (f32 accuracy, before bf16 rounding)
  cvt3_k<<<6144, 256, 0, stream>>>(wq, wk, wv, wbuf);
  gemm_bt<6><<<(M/256)*(6144/256), 512, 0, stream>>>(xa, wbuf, qb, kb, vb, fc, fs, M, 6144, D);

  transpose_k<<<4096, 256, 0, stream>>>(vb, vt);      // V[8192][2048] -> VT[2048][8192]

  attn_k<<<2048, 256, 0, stream>>>(qb, kb, vt, xa);   // O -> xa

  cvt_k<<<D*D/8/256, 256, 0, stream>>>(wo, wbuf, D*D/8);
  gemm_bt<0><<<(M/256)*(D/256), 512, 0, stream>>>(xa, wbuf, t1, nullptr, nullptr, nullptr, nullptr, M, D, D);

  rmsnorm2_k<<<M, 256, 0, stream>>>(x, t1, fnw, hf);

  cvt_k<<<HID*D/8/256, 256, 0, stream>>>(w1, wbuf, HID*D/8);
  gemm_bt<1><<<(M/256)*(HID/256), 512, 0, stream>>>(hf, wbuf, g1, nullptr, nullptr, nullptr, nullptr, M, HID, D);
  cvt_k<<<HID*D/8/256, 256, 0, stream>>>(w3, wbuf, HID*D/8);
  gemm_bt<2><<<(M/256)*(HID/256), 512, 0, stream>>>(hf, wbuf, g1, g1, nullptr, nullptr, nullptr, M, HID, D);
  cvt_k<<<HID*D/8/256, 256, 0, stream>>>(w2, wbuf, HID*D/8);
  gemm_bt<4><<<(M/256)*(D/256), 512, 0, stream>>>(g1, wbuf, out, x, t1, nullptr, nullptr, M, D, HID);
}

// Round 16
// 1121.134 us; speedup vs baseline: 1.0255x; 1.0255x over previous
//
#include <hip/hip_runtime.h>
#include <hip/hip_bf16.h>
#include <stdint.h>

typedef short  bf16x8_t __attribute__((ext_vector_type(8)));
typedef short  bf16x4_t __attribute__((ext_vector_type(4)));
typedef float  f32x4_t  __attribute__((ext_vector_type(4)));
typedef unsigned short u16;
typedef unsigned int   u32;

#define DEV __device__ __forceinline__

DEV u16 f2bf(float f){
  u32 u = __float_as_uint(f);
  u += 0x7fffu + ((u >> 16) & 1u);     // RNE
  return (u16)(u >> 16);
}
DEV float bf2f(u16 h){ return __uint_as_float(((u32)h) << 16); }

DEV void gl16(const void* g, void* l){
  __builtin_amdgcn_global_load_lds(
      (const __attribute__((address_space(1))) void*)g,
      (__attribute__((address_space(3))) void*)l, 16, 0, 0);
}

#define BAR() __builtin_amdgcn_s_barrier()
#define WL8() asm volatile("s_waitcnt lgkmcnt(8)" ::: "memory")
#define WL0() asm volatile("s_waitcnt lgkmcnt(0)" ::: "memory")

// ---------------- f32 -> bf16 convert (8 elems/thread) ----------------
__global__ __launch_bounds__(256) void cvt_k(const float* __restrict__ in,
                                             u16* __restrict__ out, int n8){
  int i = blockIdx.x * 256 + threadIdx.x;
  if (i >= n8) return;
  const float4* p = (const float4*)in;
  float4 a = p[(size_t)i*2], b = p[(size_t)i*2+1];
  bf16x8_t o;
  o[0]=(short)f2bf(a.x); o[1]=(short)f2bf(a.y); o[2]=(short)f2bf(a.z); o[3]=(short)f2bf(a.w);
  o[4]=(short)f2bf(b.x); o[5]=(short)f2bf(b.y); o[6]=(short)f2bf(b.z); o[7]=(short)f2bf(b.w);
  *(bf16x8_t*)(out + (size_t)i*8) = o;
}

// ---------------- RMSNorm: fp32 row (D=2048) -> bf16 ----------------
__global__ __launch_bounds__(256) void rmsnorm_k(const float* __restrict__ x,
                                                 const float* __restrict__ w,
                                                 u16* __restrict__ y){
  int row = blockIdx.x, t = threadIdx.x;
  const float4* xr = (const float4*)(x + (size_t)row*2048);
  float4 a = xr[t*2], b = xr[t*2+1];
  float ss = a.x*a.x+a.y*a.y+a.z*a.z+a.w*a.w + b.x*b.x+b.y*b.y+b.z*b.z+b.w*b.w;
  #pragma unroll
  for (int m = 32; m; m >>= 1) ss += __shfl_xor(ss, m, 64);
  __shared__ float red[4];
  if ((t & 63) == 0) red[t >> 6] = ss;
  __syncthreads();
  float tot = red[0]+red[1]+red[2]+red[3];
  float rs = rsqrtf(tot * (1.0f/2048.0f) + 1e-6f);
  const float4* wr = (const float4*)w;
  float4 wa = wr[t*2], wb = wr[t*2+1];
  bf16x8_t o;
  o[0]=(short)f2bf(a.x*rs*wa.x); o[1]=(short)f2bf(a.y*rs*wa.y);
  o[2]=(short)f2bf(a.z*rs*wa.z); o[3]=(short)f2bf(a.w*rs*wa.w);
  o[4]=(short)f2bf(b.x*rs*wb.x); o[5]=(short)f2bf(b.y*rs*wb.y);
  o[6]=(short)f2bf(b.z*rs*wb.z); o[7]=(short)f2bf(b.w*rs*wb.w);
  *(bf16x8_t*)(y + (size_t)row*2048 + t*8) = o;
}

// ---- RMSNorm2: h = x(f32) + t1(bf16); y = rmsnorm(h)*w -> bf16 ----
__global__ __launch_bounds__(256) void rmsnorm2_k(const float* __restrict__ x,
                                                  const u16* __restrict__ t1,
                                                  const float* __restrict__ w,
                                                  u16* __restrict__ y){
  int row = blockIdx.x, t = threadIdx.x;
  const float4* xr = (const float4*)(x + (size_t)row*2048);
  float4 a = xr[t*2], b = xr[t*2+1];
  bf16x8_t tv = *(const bf16x8_t*)(t1 + (size_t)row*2048 + t*8);
  float h[8];
  h[0]=a.x+bf2f((u16)tv[0]); h[1]=a.y+bf2f((u16)tv[1]);
  h[2]=a.z+bf2f((u16)tv[2]); h[3]=a.w+bf2f((u16)tv[3]);
  h[4]=b.x+bf2f((u16)tv[4]); h[5]=b.y+bf2f((u16)tv[5]);
  h[6]=b.z+bf2f((u16)tv[6]); h[7]=b.w+bf2f((u16)tv[7]);
  float ss = 0.f;
  #pragma unroll
  for (int j=0;j<8;j++) ss += h[j]*h[j];
  #pragma unroll
  for (int m = 32; m; m >>= 1) ss += __shfl_xor(ss, m, 64);
  __shared__ float red[4];
  if ((t & 63) == 0) red[t >> 6] = ss;
  __syncthreads();
  float tot = red[0]+red[1]+red[2]+red[3];
  float rs = rsqrtf(tot * (1.0f/2048.0f) + 1e-6f);
  const float4* wr = (const float4*)w;
  float4 wa = wr[t*2], wb = wr[t*2+1];
  bf16x8_t o;
  o[0]=(short)f2bf(h[0]*rs*wa.x); o[1]=(short)f2bf(h[1]*rs*wa.y);
  o[2]=(short)f2bf(h[2]*rs*wa.z); o[3]=(short)f2bf(h[3]*rs*wa.w);
  o[4]=(short)f2bf(h[4]*rs*wb.x); o[5]=(short)f2bf(h[5]*rs*wb.y);
  o[6]=(short)f2bf(h[6]*rs*wb.z); o[7]=(short)f2bf(h[7]*rs*wb.w);
  *(bf16x8_t*)(y + (size_t)row*2048 + t*8) = o;
}

// ---------------- RoPE in-place on q,k (bf16, B,S,H,HD) ----------------
__global__ __launch_bounds__(256) void rope_k(u16* __restrict__ q, u16* __restrict__ k,
                                              const float* __restrict__ fc,
                                              const float* __restrict__ fs){
  int i = blockIdx.x * 256 + threadIdx.x;
  int ii = i & 63; int h = (i >> 6) & 15; int bs = i >> 10;
  int s = bs & 2047;
  size_t off = (size_t)bs*2048 + h*128 + 2*ii;
  float c = fc[s*64+ii], sn = fs[s*64+ii];
  u32 qq = *(u32*)(q + off);
  float xr = bf2f((u16)(qq & 0xffff)), xi = bf2f((u16)(qq >> 16));
  *(u32*)(q + off) = (u32)f2bf(xr*c - xi*sn) | ((u32)f2bf(xr*sn + xi*c) << 16);
  u32 kk = *(u32*)(k + off);
  xr = bf2f((u16)(kk & 0xffff)); xi = bf2f((u16)(kk >> 16));
  *(u32*)(k + off) = (u32)f2bf(xr*c - xi*sn) | ((u32)f2bf(xr*sn + xi*c) << 16);
}

// ---------------- 2048x8192 transpose (V -> V^T), 64x64 tiles ----------------
__global__ __launch_bounds__(256) void transpose_k(const u16* __restrict__ in,
                                                   u16* __restrict__ out){
  __shared__ u16 tile[64*68];
  int tid = threadIdx.x;
  int tm = blockIdx.x >> 5, tn = blockIdx.x & 31;   // in: [8192][2048]
  const u16* src = in + (size_t)(tm*64)*2048 + tn*64;
  #pragma unroll
  for (int i=0;i<2;i++){
    int idx = i*256 + tid;
    int r = idx >> 3, c8 = (idx & 7)*8;
    *(bf16x8_t*)&tile[r*68 + c8] = *(const bf16x8_t*)(src + (size_t)r*2048 + c8);
  }
  __syncthreads();
  u16* dst = out + (size_t)(tn*64)*8192 + tm*64;
  #pragma unroll
  for (int i=0;i<2;i++){
    int idx = i*256 + tid;
    int oc = idx >> 3, r8 = (idx & 7)*8;
    bf16x8_t v;
    #pragma unroll
    for (int j=0;j<8;j++) v[j] = tile[(r8+j)*68 + oc];
    *(bf16x8_t*)(dst + (size_t)oc*8192 + r8) = v;
  }
}

// ---------------- GEMM: 256x256 tile, BK=64, 8-phase (r11, best) ----------
// EPI: 0 bf16; 1 silu->bf16; 2 v*aux(bf16) in-place; 4 f32 = v+aux+aux2

#define RA(BUF,MH) { \
  Ar[0][0]=*(const bf16x8_t*)(pA +BUF*16384+MH*4096);      \
  Ar[0][1]=*(const bf16x8_t*)(pAx+BUF*16384+MH*4096);      \
  Ar[1][0]=*(const bf16x8_t*)(pA +BUF*16384+MH*4096+1024); \
  Ar[1][1]=*(const bf16x8_t*)(pAx+BUF*16384+MH*4096+1024); \
  Ar[2][0]=*(const bf16x8_t*)(pA +BUF*16384+MH*4096+2048); \
  Ar[2][1]=*(const bf16x8_t*)(pAx+BUF*16384+MH*4096+2048); \
  Ar[3][0]=*(const bf16x8_t*)(pA +BUF*16384+MH*4096+3072); \
  Ar[3][1]=*(const bf16x8_t*)(pAx+BUF*16384+MH*4096+3072); }
#define RB(DST,BUF,NHL) { \
  DST[0][0]=*(const bf16x8_t*)(pB +BUF*16384+NHL*2048);      \
  DST[0][1]=*(const bf16x8_t*)(pBx+BUF*16384+NHL*2048);      \
  DST[1][0]=*(const bf16x8_t*)(pB +BUF*16384+NHL*2048+1024); \
  DST[1][1]=*(const bf16x8_t*)(pBx+BUF*16384+NHL*2048+1024); }
#define STG_A(BUF,HALF,COL) { \
  gl16(gA + (COL) + HALF*K128,       dA + BUF*16384 + HALF*8192); \
  gl16(gA + (COL) + HALF*K128 + K64, dA + BUF*16384 + HALF*8192 + 4096); }
#define STG_B(BUF,HALF,COL) { \
  gl16(gB + (COL) + HALF*K128,       dB + BUF*16384 + HALF*8192); \
  gl16(gB + (COL) + HALF*K128 + K64, dB + BUF*16384 + HALF*8192 + 4096); }

// 16 MFMA cluster, kk outermost (r11)
DEV void MMQ(bf16x8_t (&a)[4][2], bf16x8_t (&b)[2][2], int mh, int nhl,
             f32x4_t (&acc)[8][4]){
  __builtin_amdgcn_s_setprio(1);
  #pragma unroll
  for (int kk=0;kk<2;kk++)
    #pragma unroll
    for (int mi=0;mi<4;mi++)
      #pragma unroll
      for (int nj=0;nj<2;nj++)
        acc[mh*4+mi][nhl*2+nj] = __builtin_amdgcn_mfma_f32_16x16x32_bf16(
            a[mi][kk], b[nj][kk], acc[mh*4+mi][nhl*2+nj], 0,0,0);
  __builtin_amdgcn_s_setprio(0);
}

template<int EPI>
__global__ __launch_bounds__(512, 2) void gemm_bt(const u16* __restrict__ A,
                                                  const u16* __restrict__ B,
                                                  void* __restrict__ C,
                                                  const void* __restrict__ aux,
                                                  const void* __restrict__ aux2,
                                                  int M, int N, int K){
  __shared__ __align__(16) u16 sA[2][2][8192];   // [buf][rowhalf][128x64] 64KB
  __shared__ __align__(16) u16 sB[2][2][8192];   // 64KB
  int tid = threadIdx.x, lane = tid & 63, wave = tid >> 6;
  int l15 = lane & 15, l4 = lane >> 4;
  int nbn = N / 256;
  int nwg = gridDim.x, bid = blockIdx.x;
  int qq = nwg >> 3, rr = nwg & 7;
  int xc = bid & 7, yy = bid >> 3;
  int wg = (xc < rr ? xc*(qq+1) : rr*(qq+1) + (xc-rr)*qq) + yy;
  int tm = wg / nbn, tn = wg % nbn;
  size_t m0 = (size_t)tm*256, n0 = (size_t)tn*256;
  const u16* Ag = A + m0*K;
  const u16* Bg = B + n0*K;
  int wm = wave >> 2, wn = wave & 3;           // 2 x 4 wave grid
  int bh = wn >> 1, wn1 = wn & 1;

  // hoisted LDS read lane pointers (kk=0 / kk=1 chunk forms)
  int ch0 = l4 ^ (l15 & 7);
  const u16* pA  = &sA[0][wm][l15*64 + ch0*8];
  const u16* pAx = &sA[0][wm][l15*64 + (ch0^4)*8];
  const u16* pB  = &sB[0][bh][(wn1*64 + l15)*64 + ch0*8];
  const u16* pBx = &sB[0][bh][(wn1*64 + l15)*64 + (ch0^4)*8];
  // hoisted staging bases
  int r0 = tid >> 3;
  int lg = (tid & 7) ^ (r0 & 7);
  const u16* gA = Ag + (size_t)r0*K + lg*8;
  const u16* gB = Bg + (size_t)r0*K + lg*8;
  size_t K64 = (size_t)K*64, K128 = K64*2;
  u16* dA = &sA[0][0][tid*8];
  u16* dB = &sB[0][0][tid*8];

  f32x4_t acc[8][4];
  #pragma unroll
  for (int i=0;i<8;i++)
    #pragma unroll
    for (int j=0;j<4;j++)
      acc[i][j] = (f32x4_t){0.f,0.f,0.f,0.f};
  bf16x8_t Ar[4][2], Br0[2][2], Br1[2][2];
  int nk = K / 64;

  STG_A(0,0,0); STG_A(0,1,0);
  STG_B(0,0,0); STG_B(0,1,0);
  STG_B(1,0,(size_t)64); STG_B(1,1,(size_t)64);
  asm volatile("s_waitcnt vmcnt(4)" ::: "memory");
  BAR();

  for (int i=0; i<nk/2; ++i){
    int T0 = 2*i;
    bool s2 = (T0+2 < nk), s3 = (T0+3 < nk);
    size_t c1 = (size_t)(T0+1)*64, c2 = (size_t)(T0+2)*64, c3 = (size_t)(T0+3)*64;
    // p0
    RA(0,0); RB(Br0,0,0);
    STG_A(1,0,c1);
    WL8(); BAR(); WL0();
    MMQ(Ar, Br0, 0, 0, acc);
    BAR();
    // p1
    RB(Br1,0,1);
    STG_A(1,1,c1);
    BAR(); WL0();
    MMQ(Ar, Br1, 0, 1, acc);
    BAR();
    // p2
    RA(0,1);
    if (s2) STG_B(0,0,c2);
    BAR(); WL0();
    MMQ(Ar, Br0, 1, 0, acc);
    BAR();
    // p3
    if (s2){
      STG_B(0,1,c2);
      asm volatile("s_waitcnt vmcnt(4)" ::: "memory");
    } else {
      asm volatile("s_waitcnt vmcnt(0)" ::: "memory");
    }
    BAR(); WL0();
    MMQ(Ar, Br1, 1, 1, acc);
    BAR();
    // p4
    RA(1,0); RB(Br0,1,0);
    if (s2) STG_A(0,0,c2);
    WL8(); BAR(); WL0();
    MMQ(Ar, Br0, 0, 0, acc);
    BAR();
    // p5
    RB(Br1,1,1);
    if (s2) STG_A(0,1,c2);
    BAR(); WL0();
    MMQ(Ar, Br1, 0, 1, acc);
    BAR();
    // p6
    RA(1,1);
    if (s3) STG_B(1,0,c3);
    BAR(); WL0();
    MMQ(Ar, Br0, 1, 0, acc);
    BAR();
    // p7
    if (s3){
      STG_B(1,1,c3);
      asm volatile("s_waitcnt vmcnt(4)" ::: "memory");
    } else {
      asm volatile("s_waitcnt vmcnt(0)" ::: "memory");
    }
    BAR(); WL0();
    MMQ(Ar, Br1, 1, 1, acc);
    BAR();
  }

  #pragma unroll
  for (int am=0; am<8; am++)
    #pragma unroll
    for (int ni=0; ni<4; ni++)
      #pragma unroll
      for (int r=0; r<4; r++){
        float v = acc[am][ni][r];
        size_t rowg = m0 + (am&3)*16 + (am>>2)*64 + wm*128 + l4*4 + r;
        size_t colg = n0 + wn*64 + ni*16 + l15;
        size_t idx = rowg * (size_t)N + colg;
        if constexpr (EPI == 0){
          ((u16*)C)[idx] = f2bf(v);
        } else if constexpr (EPI == 1){
          float s = v / (1.0f + __expf(-v));
          ((u16*)C)[idx] = f2bf(s);
        } else if constexpr (EPI == 2){
          float a = bf2f(((const u16*)aux)[idx]);
          ((u16*)C)[idx] = f2bf(v * a);
        } else {
          float a = ((const float*)aux)[idx];
          float b2 = bf2f(((const u16*)aux2)[idx]);
          ((float*)C)[idx] = v + a + b2;
        }
      }
}

// ---------------- causal flash attention (swapped QK^T, V^T input) ----------
// Fixed-reference softmax; double-buffered K/V staging with counted vmcnt.
__global__ __launch_bounds__(256) void attn_k(const u16* __restrict__ Q,
                                              const u16* __restrict__ K,
                                              const u16* __restrict__ VT,
                                              u16* __restrict__ O){
  __shared__ __align__(16) u16 sK[2][32*128];
  __shared__ __align__(16) u16 sVT[2][128*32];
  int tid = threadIdx.x, lane = tid & 63, wave = tid >> 6;
  int bid = blockIdx.x;
  int qt = 31 - (bid >> 6);
  int bh = bid & 63; int b = bh >> 4, h = bh & 15;
  int l15 = lane & 15, l4 = lane >> 4;
  size_t base = ((size_t)b*2048)*2048 + (size_t)h*128;
  const u16* VTg0 = VT + ((size_t)h*128)*8192 + (size_t)b*2048;
  int qr0 = qt*64 + wave*16;
  int qrow = qr0 + l15;
  bf16x8_t qf[4];
  #pragma unroll
  for (int s=0;s<4;s++)
    qf[s] = *(const bf16x8_t*)(Q + base + (size_t)qrow*2048 + s*32 + l4*8);

  f32x4_t oaccT[8];
  #pragma unroll
  for (int f=0;f<8;f++) oaccT[f] = (f32x4_t){0.f,0.f,0.f,0.f};
  float lrun = 0.f;

  const float cl2 = 0.08838834764831845f * 1.4426950408889634f;
  int nkt = (qt + 1) * 2;

  auto STG = [&](int t, int buf){
    const u16* Kg = K + base + (size_t)t*32*2048;
    #pragma unroll
    for (int i=0;i<2;i++){
      int c = i*256 + tid; int row = c>>4;
      gl16(Kg + (size_t)row*2048 + (size_t)(((c&15) ^ (row&7))*8), &sK[buf][c*8]);
    }
    #pragma unroll
    for (int i=0;i<2;i++){
      int c = i*256 + tid; int d = c>>2;
      gl16(VTg0 + (size_t)d*8192 + t*32 + (size_t)((((c&3) ^ ((d>>1)&3)))*8),
           &sVT[buf][c*8]);
    }
  };

  STG(0, 0);
  STG(1, 1);     // nkt >= 2 always

  for (int kt=0; kt<nkt; ++kt){
    if (kt < nkt-1) asm volatile("s_waitcnt vmcnt(4)" ::: "memory");
    else            asm volatile("s_waitcnt vmcnt(0)" ::: "memory");
    BAR();
    int buf = kt & 1;
    if (kt*32 <= qr0 + 15){
      f32x4_t sacc[2];
      sacc[0] = (f32x4_t){0.f,0.f,0.f,0.f};
      sacc[1] = (f32x4_t){0.f,0.f,0.f,0.f};
      __builtin_amdgcn_s_setprio(1);
      #pragma unroll
      for (int n=0;n<2;n++)
        #pragma unroll
        for (int s=0;s<4;s++){
          bf16x8_t kf = *(const bf16x8_t*)
              &sK[buf][(n*16 + l15)*128 + (((s*4 + l4) ^ (l15 & 7))*8)];
          sacc[n] = __builtin_amdgcn_mfma_f32_16x16x32_bf16(kf, qf[s], sacc[n], 0,0,0);
        }
      __builtin_amdgcn_s_setprio(0);
      float sum = 0.f;
      bf16x8_t pa;
      bool diag = (kt*32 + 31 > qr0);
      if (diag){
        #pragma unroll
        for (int j=0;j<8;j++){
          int n = j>>2, r = j&3;
          float p = exp2f(sacc[n][r] * cl2);
          int kg = kt*32 + n*16 + l4*4 + r;
          if (kg > qrow) p = 0.f;
          sum += p;
          pa[j] = (short)f2bf(p);
        }
      } else {
        #pragma unroll
        for (int j=0;j<8;j++){
          float p = exp2f(sacc[j>>2][j&3] * cl2);
          sum += p;
          pa[j] = (short)f2bf(p);
        }
      }
      sum += __shfl_xor(sum, 16, 64);
      sum += __shfl_xor(sum, 32, 64);
      lrun += sum;
      __builtin_amdgcn_s_setprio(1);
      #pragma unroll
      for (int f=0;f<8;f++){
        int d = f*16 + l15;
        bf16x4_t lo = *(const bf16x4_t*)&sVT[buf][d*32 + (((0*4 + l4) ^ (d & 6))*4)];
        bf16x4_t hi = *(const bf16x4_t*)&sVT[buf][d*32 + (((1*4 + l4) ^ (d & 6))*4)];
        bf16x8_t va;
        va[0]=lo[0]; va[1]=lo[1]; va[2]=lo[2]; va[3]=lo[3];
        va[4]=hi[0]; va[5]=hi[1]; va[6]=hi[2]; va[7]=hi[3];
        oaccT[f] = __builtin_amdgcn_mfma_f32_16x16x32_bf16(va, pa, oaccT[f], 0,0,0);
      }
      __builtin_amdgcn_s_setprio(0);
    }
    BAR();
    if (kt+2 < nkt) STG(kt+2, buf);
  }
  float inv = 1.0f / lrun;
  size_t orow = (size_t)b*2048 + qrow;
  #pragma unroll
  for (int f=0;f<8;f++){
    bf16x4_t ov;
    ov[0]=(short)f2bf(oaccT[f][0]*inv); ov[1]=(short)f2bf(oaccT[f][1]*inv);
    ov[2]=(short)f2bf(oaccT[f][2]*inv); ov[3]=(short)f2bf(oaccT[f][3]*inv);
    *(bf16x4_t*)(O + orow*2048 + h*128 + f*16 + l4*4) = ov;
  }
}

// ---------------- host ----------------
extern "C" void kernel_launch(void* const* d_in, const int* in_sizes, int n_in,
                              void* d_out, int out_size, void* d_ws, size_t ws_size,
                              hipStream_t stream){
  (void)in_sizes; (void)n_in; (void)out_size; (void)ws_size;
  const float* x   = (const float*)d_in[0];
  const float* fc  = (const float*)d_in[1];
  const float* fs  = (const float*)d_in[2];
  const float* wq  = (const float*)d_in[4];
  const float* wk  = (const float*)d_in[5];
  const float* wv  = (const float*)d_in[6];
  const float* wo  = (const float*)d_in[7];
  const float* w1  = (const float*)d_in[8];
  const float* w2  = (const float*)d_in[9];
  const float* w3  = (const float*)d_in[10];
  const float* anw = (const float*)d_in[11];
  const float* fnw = (const float*)d_in[12];
  float* out = (float*)d_out;
  char* ws = (char*)d_ws;

  const int M = 8192, D = 2048, HID = 5632;
  const size_t WB   = 23068672ull;   // 5632*2048*2 (reused weight buf)
  const size_t ACT2 = 33554432ull;   // 8192*2048*2

  u16* wbuf = (u16*)(ws);
  u16* xa   = (u16*)(ws + WB);                // rmsnorm(x); later attn O
  u16* qb   = (u16*)(ws + WB + ACT2);         // Q; later t1 = o@wo^T
  u16* kb   = (u16*)(ws + WB + 2*ACT2);       // K; later hf
  u16* vb   = (u16*)(ws + WB + 3*ACT2);       // V
  u16* g1   = (u16*)(ws + WB + 4*ACT2);       // VT (32MB) then g1 (88 MiB)
  u16* vt = g1;
  u16* t1 = qb;
  u16* hf = kb;

  rmsnorm_k<<<M, 256, 0, stream>>>(x, anw, xa);

  cvt_k<<<D*D/8/256, 256, 0, stream>>>(wq, wbuf, D*D/8);
  gemm_bt<0><<<(M/256)*(D/256), 512, 0, stream>>>(xa, wbuf, qb, nullptr, nullptr, M, D, D);
  cvt_k<<<D*D/8/256, 256, 0, stream>>>(wk, wbuf, D*D/8);
  gemm_bt<0><<<(M/256)*(D/256), 512, 0, stream>>>(xa, wbuf, kb, nullptr, nullptr, M, D, D);
  cvt_k<<<D*D/8/256, 256, 0, stream>>>(wv, wbuf, D*D/8);
  gemm_bt<0><<<(M/256)*(D/256), 512, 0, stream>>>(xa, wbuf, vb, nullptr, nullptr, M, D, D);

  rope_k<<<32768, 256, 0, stream>>>(qb, kb, fc, fs);
  transpose_k<<<4096, 256, 0, stream>>>(vb, vt);      // V[8192][2048] -> VT[2048][8192]

  attn_k<<<2048, 256, 0, stream>>>(qb, kb, vt, xa);   // O -> xa

  cvt_k<<<D*D/8/256, 256, 0, stream>>>(wo, wbuf, D*D/8);
  gemm_bt<0><<<(M/256)*(D/256), 512, 0, stream>>>(xa, wbuf, t1, nullptr, nullptr, M, D, D);

  rmsnorm2_k<<<M, 256, 0, stream>>>(x, t1, fnw, hf);

  cvt_k<<<HID*D/8/256, 256, 0, stream>>>(w1, wbuf, HID*D/8);
  gemm_bt<1><<<(M/256)*(HID/256), 512, 0, stream>>>(hf, wbuf, g1, nullptr, nullptr, M, HID, D);
  cvt_k<<<HID*D/8/256, 256, 0, stream>>>(w3, wbuf, HID*D/8);
  gemm_bt<2><<<(M/256)*(HID/256), 512, 0, stream>>>(hf, wbuf, g1, g1, nullptr, M, HID, D);
  cvt_k<<<HID*D/8/256, 256, 0, stream>>>(w2, wbuf, HID*D/8);
  gemm_bt<4><<<(M/256)*(D/256), 512, 0, stream>>>(g1, wbuf, out, x, t1, M, D, HID);
}

// Round 17
// 1120.772 us; speedup vs baseline: 1.0259x; 1.0003x over previous
//
#include <hip/hip_runtime.h>
#include <hip/hip_bf16.h>
#include <stdint.h>

typedef short  bf16x8_t __attribute__((ext_vector_type(8)));
typedef short  bf16x4_t __attribute__((ext_vector_type(4)));
typedef float  f32x4_t  __attribute__((ext_vector_type(4)));
typedef unsigned short u16;
typedef unsigned int   u32;

#define DEV __device__ __forceinline__

DEV u16 f2bf(float f){
  u32 u = __float_as_uint(f);
  u += 0x7fffu + ((u >> 16) & 1u);     // RNE
  return (u16)(u >> 16);
}
DEV float bf2f(u16 h){ return __uint_as_float(((u32)h) << 16); }

DEV void gl16(const void* g, void* l){
  __builtin_amdgcn_global_load_lds(
      (const __attribute__((address_space(1))) void*)g,
      (__attribute__((address_space(3))) void*)l, 16, 0, 0);
}

#define BAR() __builtin_amdgcn_s_barrier()
#define CF()  asm volatile("" ::: "memory")   // compiler-only fence (0 instrs)

// ---------------- f32 -> bf16 convert (8 elems/thread) ----------------
__global__ __launch_bounds__(256) void cvt_k(const float* __restrict__ in,
                                             u16* __restrict__ out, int n8){
  int i = blockIdx.x * 256 + threadIdx.x;
  if (i >= n8) return;
  const float4* p = (const float4*)in;
  float4 a = p[(size_t)i*2], b = p[(size_t)i*2+1];
  bf16x8_t o;
  o[0]=(short)f2bf(a.x); o[1]=(short)f2bf(a.y); o[2]=(short)f2bf(a.z); o[3]=(short)f2bf(a.w);
  o[4]=(short)f2bf(b.x); o[5]=(short)f2bf(b.y); o[6]=(short)f2bf(b.z); o[7]=(short)f2bf(b.w);
  *(bf16x8_t*)(out + (size_t)i*8) = o;
}

// ---------------- RMSNorm: fp32 row (D=2048) -> bf16 ----------------
__global__ __launch_bounds__(256) void rmsnorm_k(const float* __restrict__ x,
                                                 const float* __restrict__ w,
                                                 u16* __restrict__ y){
  int row = blockIdx.x, t = threadIdx.x;
  const float4* xr = (const float4*)(x + (size_t)row*2048);
  float4 a = xr[t*2], b = xr[t*2+1];
  float ss = a.x*a.x+a.y*a.y+a.z*a.z+a.w*a.w + b.x*b.x+b.y*b.y+b.z*b.z+b.w*b.w;
  #pragma unroll
  for (int m = 32; m; m >>= 1) ss += __shfl_xor(ss, m, 64);
  __shared__ float red[4];
  if ((t & 63) == 0) red[t >> 6] = ss;
  __syncthreads();
  float tot = red[0]+red[1]+red[2]+red[3];
  float rs = rsqrtf(tot * (1.0f/2048.0f) + 1e-6f);
  const float4* wr = (const float4*)w;
  float4 wa = wr[t*2], wb = wr[t*2+1];
  bf16x8_t o;
  o[0]=(short)f2bf(a.x*rs*wa.x); o[1]=(short)f2bf(a.y*rs*wa.y);
  o[2]=(short)f2bf(a.z*rs*wa.z); o[3]=(short)f2bf(a.w*rs*wa.w);
  o[4]=(short)f2bf(b.x*rs*wb.x); o[5]=(short)f2bf(b.y*rs*wb.y);
  o[6]=(short)f2bf(b.z*rs*wb.z); o[7]=(short)f2bf(b.w*rs*wb.w);
  *(bf16x8_t*)(y + (size_t)row*2048 + t*8) = o;
}

// ---- RMSNorm2: h = x(f32) + t1(bf16); y = rmsnorm(h)*w -> bf16 ----
__global__ __launch_bounds__(256) void rmsnorm2_k(const float* __restrict__ x,
                                                  const u16* __restrict__ t1,
                                                  const float* __restrict__ w,
                                                  u16* __restrict__ y){
  int row = blockIdx.x, t = threadIdx.x;
  const float4* xr = (const float4*)(x + (size_t)row*2048);
  float4 a = xr[t*2], b = xr[t*2+1];
  bf16x8_t tv = *(const bf16x8_t*)(t1 + (size_t)row*2048 + t*8);
  float h[8];
  h[0]=a.x+bf2f((u16)tv[0]); h[1]=a.y+bf2f((u16)tv[1]);
  h[2]=a.z+bf2f((u16)tv[2]); h[3]=a.w+bf2f((u16)tv[3]);
  h[4]=b.x+bf2f((u16)tv[4]); h[5]=b.y+bf2f((u16)tv[5]);
  h[6]=b.z+bf2f((u16)tv[6]); h[7]=b.w+bf2f((u16)tv[7]);
  float ss = 0.f;
  #pragma unroll
  for (int j=0;j<8;j++) ss += h[j]*h[j];
  #pragma unroll
  for (int m = 32; m; m >>= 1) ss += __shfl_xor(ss, m, 64);
  __shared__ float red[4];
  if ((t & 63) == 0) red[t >> 6] = ss;
  __syncthreads();
  float tot = red[0]+red[1]+red[2]+red[3];
  float rs = rsqrtf(tot * (1.0f/2048.0f) + 1e-6f);
  const float4* wr = (const float4*)w;
  float4 wa = wr[t*2], wb = wr[t*2+1];
  bf16x8_t o;
  o[0]=(short)f2bf(h[0]*rs*wa.x); o[1]=(short)f2bf(h[1]*rs*wa.y);
  o[2]=(short)f2bf(h[2]*rs*wa.z); o[3]=(short)f2bf(h[3]*rs*wa.w);
  o[4]=(short)f2bf(h[4]*rs*wb.x); o[5]=(short)f2bf(h[5]*rs*wb.y);
  o[6]=(short)f2bf(h[6]*rs*wb.z); o[7]=(short)f2bf(h[7]*rs*wb.w);
  *(bf16x8_t*)(y + (size_t)row*2048 + t*8) = o;
}

// ---------------- RoPE in-place on q,k (bf16, B,S,H,HD) ----------------
__global__ __launch_bounds__(256) void rope_k(u16* __restrict__ q, u16* __restrict__ k,
                                              const float* __restrict__ fc,
                                              const float* __restrict__ fs){
  int i = blockIdx.x * 256 + threadIdx.x;
  int ii = i & 63; int h = (i >> 6) & 15; int bs = i >> 10;
  int s = bs & 2047;
  size_t off = (size_t)bs*2048 + h*128 + 2*ii;
  float c = fc[s*64+ii], sn = fs[s*64+ii];
  u32 qq = *(u32*)(q + off);
  float xr = bf2f((u16)(qq & 0xffff)), xi = bf2f((u16)(qq >> 16));
  *(u32*)(q + off) = (u32)f2bf(xr*c - xi*sn) | ((u32)f2bf(xr*sn + xi*c) << 16);
  u32 kk = *(u32*)(k + off);
  xr = bf2f((u16)(kk & 0xffff)); xi = bf2f((u16)(kk >> 16));
  *(u32*)(k + off) = (u32)f2bf(xr*c - xi*sn) | ((u32)f2bf(xr*sn + xi*c) << 16);
}

// ---------------- 2048x8192 transpose (V -> V^T), 64x64 tiles ----------------
__global__ __launch_bounds__(256) void transpose_k(const u16* __restrict__ in,
                                                   u16* __restrict__ out){
  __shared__ u16 tile[64*68];
  int tid = threadIdx.x;
  int tm = blockIdx.x >> 5, tn = blockIdx.x & 31;   // in: [8192][2048]
  const u16* src = in + (size_t)(tm*64)*2048 + tn*64;
  #pragma unroll
  for (int i=0;i<2;i++){
    int idx = i*256 + tid;
    int r = idx >> 3, c8 = (idx & 7)*8;
    *(bf16x8_t*)&tile[r*68 + c8] = *(const bf16x8_t*)(src + (size_t)r*2048 + c8);
  }
  __syncthreads();
  u16* dst = out + (size_t)(tn*64)*8192 + tm*64;
  #pragma unroll
  for (int i=0;i<2;i++){
    int idx = i*256 + tid;
    int oc = idx >> 3, r8 = (idx & 7)*8;
    bf16x8_t v;
    #pragma unroll
    for (int j=0;j<8;j++) v[j] = tile[(r8+j)*68 + oc];
    *(bf16x8_t*)(dst + (size_t)oc*8192 + r8) = v;
  }
}

// ---------------- GEMM: 256x256 tile, BK=64, 8-phase ----------------------
// r11 ledger; per-phase lgkmcnt(0) drains REMOVED — compiler emits
// fine-grained lgkm waits per MFMA operand. Compiler fences (CF) pin LDS
// reads to the correct side of each barrier without pinning instr order.
// EPI: 0 bf16; 1 silu->bf16; 2 v*aux(bf16) in-place; 4 f32 = v+aux+aux2

#define RA(BUF,MH) { \
  Ar[0][0]=*(const bf16x8_t*)(pA +BUF*16384+MH*4096);      \
  Ar[0][1]=*(const bf16x8_t*)(pAx+BUF*16384+MH*4096);      \
  Ar[1][0]=*(const bf16x8_t*)(pA +BUF*16384+MH*4096+1024); \
  Ar[1][1]=*(const bf16x8_t*)(pAx+BUF*16384+MH*4096+1024); \
  Ar[2][0]=*(const bf16x8_t*)(pA +BUF*16384+MH*4096+2048); \
  Ar[2][1]=*(const bf16x8_t*)(pAx+BUF*16384+MH*4096+2048); \
  Ar[3][0]=*(const bf16x8_t*)(pA +BUF*16384+MH*4096+3072); \
  Ar[3][1]=*(const bf16x8_t*)(pAx+BUF*16384+MH*4096+3072); }
#define RB(DST,BUF,NHL) { \
  DST[0][0]=*(const bf16x8_t*)(pB +BUF*16384+NHL*2048);      \
  DST[0][1]=*(const bf16x8_t*)(pBx+BUF*16384+NHL*2048);      \
  DST[1][0]=*(const bf16x8_t*)(pB +BUF*16384+NHL*2048+1024); \
  DST[1][1]=*(const bf16x8_t*)(pBx+BUF*16384+NHL*2048+1024); }
#define STG_A(BUF,HALF,COL) { \
  gl16(gA + (COL) + HALF*K128,       dA + BUF*16384 + HALF*8192); \
  gl16(gA + (COL) + HALF*K128 + K64, dA + BUF*16384 + HALF*8192 + 4096); }
#define STG_B(BUF,HALF,COL) { \
  gl16(gB + (COL) + HALF*K128,       dB + BUF*16384 + HALF*8192); \
  gl16(gB + (COL) + HALF*K128 + K64, dB + BUF*16384 + HALF*8192 + 4096); }

// 16 MFMA cluster, kk outermost (r11)
DEV void MMQ(bf16x8_t (&a)[4][2], bf16x8_t (&b)[2][2], int mh, int nhl,
             f32x4_t (&acc)[8][4]){
  __builtin_amdgcn_s_setprio(1);
  #pragma unroll
  for (int kk=0;kk<2;kk++)
    #pragma unroll
    for (int mi=0;mi<4;mi++)
      #pragma unroll
      for (int nj=0;nj<2;nj++)
        acc[mh*4+mi][nhl*2+nj] = __builtin_amdgcn_mfma_f32_16x16x32_bf16(
            a[mi][kk], b[nj][kk], acc[mh*4+mi][nhl*2+nj], 0,0,0);
  __builtin_amdgcn_s_setprio(0);
}

template<int EPI>
__global__ __launch_bounds__(512, 2) void gemm_bt(const u16* __restrict__ A,
                                                  const u16* __restrict__ B,
                                                  void* __restrict__ C,
                                                  const void* __restrict__ aux,
                                                  const void* __restrict__ aux2,
                                                  int M, int N, int K){
  __shared__ __align__(16) u16 sA[2][2][8192];   // [buf][rowhalf][128x64] 64KB
  __shared__ __align__(16) u16 sB[2][2][8192];   // 64KB
  int tid = threadIdx.x, lane = tid & 63, wave = tid >> 6;
  int l15 = lane & 15, l4 = lane >> 4;
  int nbn = N / 256;
  int nwg = gridDim.x, bid = blockIdx.x;
  int qq = nwg >> 3, rr = nwg & 7;
  int xc = bid & 7, yy = bid >> 3;
  int wg = (xc < rr ? xc*(qq+1) : rr*(qq+1) + (xc-rr)*qq) + yy;
  int tm = wg / nbn, tn = wg % nbn;
  size_t m0 = (size_t)tm*256, n0 = (size_t)tn*256;
  const u16* Ag = A + m0*K;
  const u16* Bg = B + n0*K;
  int wm = wave >> 2, wn = wave & 3;           // 2 x 4 wave grid
  int bh = wn >> 1, wn1 = wn & 1;

  // hoisted LDS read lane pointers (kk=0 / kk=1 chunk forms)
  int ch0 = l4 ^ (l15 & 7);
  const u16* pA  = &sA[0][wm][l15*64 + ch0*8];
  const u16* pAx = &sA[0][wm][l15*64 + (ch0^4)*8];
  const u16* pB  = &sB[0][bh][(wn1*64 + l15)*64 + ch0*8];
  const u16* pBx = &sB[0][bh][(wn1*64 + l15)*64 + (ch0^4)*8];
  // hoisted staging bases
  int r0 = tid >> 3;
  int lg = (tid & 7) ^ (r0 & 7);
  const u16* gA = Ag + (size_t)r0*K + lg*8;
  const u16* gB = Bg + (size_t)r0*K + lg*8;
  size_t K64 = (size_t)K*64, K128 = K64*2;
  u16* dA = &sA[0][0][tid*8];
  u16* dB = &sB[0][0][tid*8];

  f32x4_t acc[8][4];
  #pragma unroll
  for (int i=0;i<8;i++)
    #pragma unroll
    for (int j=0;j<4;j++)
      acc[i][j] = (f32x4_t){0.f,0.f,0.f,0.f};
  bf16x8_t Ar[4][2], Br0[2][2], Br1[2][2];
  int nk = K / 64;

  STG_A(0,0,0); STG_A(0,1,0);
  STG_B(0,0,0); STG_B(0,1,0);
  STG_B(1,0,(size_t)64); STG_B(1,1,(size_t)64);
  asm volatile("s_waitcnt vmcnt(4)" ::: "memory");
  BAR(); CF();

  for (int i=0; i<nk/2; ++i){
    int T0 = 2*i;
    bool s2 = (T0+2 < nk), s3 = (T0+3 < nk);
    size_t c1 = (size_t)(T0+1)*64, c2 = (size_t)(T0+2)*64, c3 = (size_t)(T0+3)*64;
    // p0
    RA(0,0); RB(Br0,0,0);
    STG_A(1,0,c1);
    CF(); BAR(); CF();
    MMQ(Ar, Br0, 0, 0, acc);
    CF(); BAR(); CF();
    // p1
    RB(Br1,0,1);
    STG_A(1,1,c1);
    CF(); BAR(); CF();
    MMQ(Ar, Br1, 0, 1, acc);
    CF(); BAR(); CF();
    // p2
    RA(0,1);
    if (s2) STG_B(0,0,c2);
    CF(); BAR(); CF();
    MMQ(Ar, Br0, 1, 0, acc);
    CF(); BAR(); CF();
    // p3
    if (s2){
      STG_B(0,1,c2);
      asm volatile("s_waitcnt vmcnt(4)" ::: "memory");
    } else {
      asm volatile("s_waitcnt vmcnt(0)" ::: "memory");
    }
    CF(); BAR(); CF();
    MMQ(Ar, Br1, 1, 1, acc);
    CF(); BAR(); CF();
    // p4
    RA(1,0); RB(Br0,1,0);
    if (s2) STG_A(0,0,c2);
    CF(); BAR(); CF();
    MMQ(Ar, Br0, 0, 0, acc);
    CF(); BAR(); CF();
    // p5
    RB(Br1,1,1);
    if (s2) STG_A(0,1,c2);
    CF(); BAR(); CF();
    MMQ(Ar, Br1, 0, 1, acc);
    CF(); BAR(); CF();
    // p6
    RA(1,1);
    if (s3) STG_B(1,0,c3);
    CF(); BAR(); CF();
    MMQ(Ar, Br0, 1, 0, acc);
    CF(); BAR(); CF();
    // p7
    if (s3){
      STG_B(1,1,c3);
      asm volatile("s_waitcnt vmcnt(4)" ::: "memory");
    } else {
      asm volatile("s_waitcnt vmcnt(0)" ::: "memory");
    }
    CF(); BAR(); CF();
    MMQ(Ar, Br1, 1, 1, acc);
    CF(); BAR(); CF();
  }

  #pragma unroll
  for (int am=0; am<8; am++)
    #pragma unroll
    for (int ni=0; ni<4; ni++)
      #pragma unroll
      for (int r=0; r<4; r++){
        float v = acc[am][ni][r];
        size_t rowg = m0 + (am&3)*16 + (am>>2)*64 + wm*128 + l4*4 + r;
        size_t colg = n0 + wn*64 + ni*16 + l15;
        size_t idx = rowg * (size_t)N + colg;
        if constexpr (EPI == 0){
          ((u16*)C)[idx] = f2bf(v);
        } else if constexpr (EPI == 1){
          float s = v / (1.0f + __expf(-v));
          ((u16*)C)[idx] = f2bf(s);
        } else if constexpr (EPI == 2){
          float a = bf2f(((const u16*)aux)[idx]);
          ((u16*)C)[idx] = f2bf(v * a);
        } else {
          float a = ((const float*)aux)[idx];
          float b2 = bf2f(((const u16*)aux2)[idx]);
          ((float*)C)[idx] = v + a + b2;
        }
      }
}

// ---------------- causal flash attention (swapped QK^T, V^T input) ----------
// Fixed-reference softmax; double-buffered K/V staging with counted vmcnt.
__global__ __launch_bounds__(256) void attn_k(const u16* __restrict__ Q,
                                              const u16* __restrict__ K,
                                              const u16* __restrict__ VT,
                                              u16* __restrict__ O){
  __shared__ __align__(16) u16 sK[2][32*128];
  __shared__ __align__(16) u16 sVT[2][128*32];
  int tid = threadIdx.x, lane = tid & 63, wave = tid >> 6;
  int bid = blockIdx.x;
  int qt = 31 - (bid >> 6);
  int bh = bid & 63; int b = bh >> 4, h = bh & 15;
  int l15 = lane & 15, l4 = lane >> 4;
  size_t base = ((size_t)b*2048)*2048 + (size_t)h*128;
  const u16* VTg0 = VT + ((size_t)h*128)*8192 + (size_t)b*2048;
  int qr0 = qt*64 + wave*16;
  int qrow = qr0 + l15;
  bf16x8_t qf[4];
  #pragma unroll
  for (int s=0;s<4;s++)
    qf[s] = *(const bf16x8_t*)(Q + base + (size_t)qrow*2048 + s*32 + l4*8);

  f32x4_t oaccT[8];
  #pragma unroll
  for (int f=0;f<8;f++) oaccT[f] = (f32x4_t){0.f,0.f,0.f,0.f};
  float lrun = 0.f;

  const float cl2 = 0.08838834764831845f * 1.4426950408889634f;
  int nkt = (qt + 1) * 2;

  auto STG = [&](int t, int buf){
    const u16* Kg = K + base + (size_t)t*32*2048;
    #pragma unroll
    for (int i=0;i<2;i++){
      int c = i*256 + tid; int row = c>>4;
      gl16(Kg + (size_t)row*2048 + (size_t)(((c&15) ^ (row&7))*8), &sK[buf][c*8]);
    }
    #pragma unroll
    for (int i=0;i<2;i++){
      int c = i*256 + tid; int d = c>>2;
      gl16(VTg0 + (size_t)d*8192 + t*32 + (size_t)((((c&3) ^ ((d>>1)&3)))*8),
           &sVT[buf][c*8]);
    }
  };

  STG(0, 0);
  STG(1, 1);     // nkt >= 2 always

  for (int kt=0; kt<nkt; ++kt){
    if (kt < nkt-1) asm volatile("s_waitcnt vmcnt(4)" ::: "memory");
    else            asm volatile("s_waitcnt vmcnt(0)" ::: "memory");
    BAR(); CF();
    int buf = kt & 1;
    if (kt*32 <= qr0 + 15){
      f32x4_t sacc[2];
      sacc[0] = (f32x4_t){0.f,0.f,0.f,0.f};
      sacc[1] = (f32x4_t){0.f,0.f,0.f,0.f};
      __builtin_amdgcn_s_setprio(1);
      #pragma unroll
      for (int n=0;n<2;n++)
        #pragma unroll
        for (int s=0;s<4;s++){
          bf16x8_t kf = *(const bf16x8_t*)
              &sK[buf][(n*16 + l15)*128 + (((s*4 + l4) ^ (l15 & 7))*8)];
          sacc[n] = __builtin_amdgcn_mfma_f32_16x16x32_bf16(kf, qf[s], sacc[n], 0,0,0);
        }
      __builtin_amdgcn_s_setprio(0);
      float sum = 0.f;
      bf16x8_t pa;
      bool diag = (kt*32 + 31 > qr0);
      if (diag){
        #pragma unroll
        for (int j=0;j<8;j++){
          int n = j>>2, r = j&3;
          float p = exp2f(sacc[n][r] * cl2);
          int kg = kt*32 + n*16 + l4*4 + r;
          if (kg > qrow) p = 0.f;
          sum += p;
          pa[j] = (short)f2bf(p);
        }
      } else {
        #pragma unroll
        for (int j=0;j<8;j++){
          float p = exp2f(sacc[j>>2][j&3] * cl2);
          sum += p;
          pa[j] = (short)f2bf(p);
        }
      }
      sum += __shfl_xor(sum, 16, 64);
      sum += __shfl_xor(sum, 32, 64);
      lrun += sum;
      __builtin_amdgcn_s_setprio(1);
      #pragma unroll
      for (int f=0;f<8;f++){
        int d = f*16 + l15;
        bf16x4_t lo = *(const bf16x4_t*)&sVT[buf][d*32 + (((0*4 + l4) ^ (d & 6))*4)];
        bf16x4_t hi = *(const bf16x4_t*)&sVT[buf][d*32 + (((1*4 + l4) ^ (d & 6))*4)];
        bf16x8_t va;
        va[0]=lo[0]; va[1]=lo[1]; va[2]=lo[2]; va[3]=lo[3];
        va[4]=hi[0]; va[5]=hi[1]; va[6]=hi[2]; va[7]=hi[3];
        oaccT[f] = __builtin_amdgcn_mfma_f32_16x16x32_bf16(va, pa, oaccT[f], 0,0,0);
      }
      __builtin_amdgcn_s_setprio(0);
    }
    CF(); BAR(); CF();
    if (kt+2 < nkt) STG(kt+2, buf);
  }
  float inv = 1.0f / lrun;
  size_t orow = (size_t)b*2048 + qrow;
  #pragma unroll
  for (int f=0;f<8;f++){
    bf16x4_t ov;
    ov[0]=(short)f2bf(oaccT[f][0]*inv); ov[1]=(short)f2bf(oaccT[f][1]*inv);
    ov[2]=(short)f2bf(oaccT[f][2]*inv); ov[3]=(short)f2bf(oaccT[f][3]*inv);
    *(bf16x4_t*)(O + orow*2048 + h*128 + f*16 + l4*4) = ov;
  }
}

// ---------------- host ----------------
extern "C" void kernel_launch(void* const* d_in, const int* in_sizes, int n_in,
                              void* d_out, int out_size, void* d_ws, size_t ws_size,
                              hipStream_t stream){
  (void)in_sizes; (void)n_in; (void)out_size; (void)ws_size;
  const float* x   = (const float*)d_in[0];
  const float* fc  = (const float*)d_in[1];
  const float* fs  = (const float*)d_in[2];
  const float* wq  = (const float*)d_in[4];
  const float* wk  = (const float*)d_in[5];
  const float* wv  = (const float*)d_in[6];
  const float* wo  = (const float*)d_in[7];
  const float* w1  = (const float*)d_in[8];
  const float* w2  = (const float*)d_in[9];
  const float* w3  = (const float*)d_in[10];
  const float* anw = (const float*)d_in[11];
  const float* fnw = (const float*)d_in[12];
  float* out = (float*)d_out;
  char* ws = (char*)d_ws;

  const int M = 8192, D = 2048, HID = 5632;
  const size_t WB   = 23068672ull;   // 5632*2048*2 (reused weight buf)
  const size_t ACT2 = 33554432ull;   // 8192*2048*2

  u16* wbuf = (u16*)(ws);
  u16* xa   = (u16*)(ws + WB);                // rmsnorm(x); later attn O
  u16* qb   = (u16*)(ws + WB + ACT2);         // Q; later t1 = o@wo^T
  u16* kb   = (u16*)(ws + WB + 2*ACT2);       // K; later hf
  u16* vb   = (u16*)(ws + WB + 3*ACT2);       // V
  u16* g1   = (u16*)(ws + WB + 4*ACT2);       // VT (32MB) then g1 (88 MiB)
  u16* vt = g1;
  u16* t1 = qb;
  u16* hf = kb;

  rmsnorm_k<<<M, 256, 0, stream>>>(x, anw, xa);

  cvt_k<<<D*D/8/256, 256, 0, stream>>>(wq, wbuf, D*D/8);
  gemm_bt<0><<<(M/256)*(D/256), 512, 0, stream>>>(xa, wbuf, qb, nullptr, nullptr, M, D, D);
  cvt_k<<<D*D/8/256, 256, 0, stream>>>(wk, wbuf, D*D/8);
  gemm_bt<0><<<(M/256)*(D/256), 512, 0, stream>>>(xa, wbuf, kb, nullptr, nullptr, M, D, D);
  cvt_k<<<D*D/8/256, 256, 0, stream>>>(wv, wbuf, D*D/8);
  gemm_bt<0><<<(M/256)*(D/256), 512, 0, stream>>>(xa, wbuf, vb, nullptr, nullptr, M, D, D);

  rope_k<<<32768, 256, 0, stream>>>(qb, kb, fc, fs);
  transpose_k<<<4096, 256, 0, stream>>>(vb, vt);      // V[8192][2048] -> VT[2048][8192]

  attn_k<<<2048, 256, 0, stream>>>(qb, kb, vt, xa);   // O -> xa

  cvt_k<<<D*D/8/256, 256, 0, stream>>>(wo, wbuf, D*D/8);
  gemm_bt<0><<<(M/256)*(D/256), 512, 0, stream>>>(xa, wbuf, t1, nullptr, nullptr, M, D, D);

  rmsnorm2_k<<<M, 256, 0, stream>>>(x, t1, fnw, hf);

  cvt_k<<<HID*D/8/256, 256, 0, stream>>>(w1, wbuf, HID*D/8);
  gemm_bt<1><<<(M/256)*(HID/256), 512, 0, stream>>>(hf, wbuf, g1, nullptr, nullptr, M, HID, D);
  cvt_k<<<HID*D/8/256, 256, 0, stream>>>(w3, wbuf, HID*D/8);
  gemm_bt<2><<<(M/256)*(HID/256), 512, 0, stream>>>(hf, wbuf, g1, g1, nullptr, M, HID, D);
  cvt_k<<<HID*D/8/256, 256, 0, stream>>>(w2, wbuf, HID*D/8);
  gemm_bt<4><<<(M/256)*(D/256), 512, 0, stream>>>(g1, wbuf, out, x, t1, M, D, HID);
}